// Round 7
// baseline (254.358 us; speedup 1.0000x reference)
//
#include <hip/hip_runtime.h>

// ---------------- problem constants ----------------
#define NQ        300
#define NC        80
#define NE        24000      // NQ*NC
#define CAND      1000
#define KSEL      100
#define NPAIRS    4000000
#define HBN       65536      // histogram buckets, bits>>14 (max 0x3F7FFFFF>>14 = 65023)
#define FHW       65536      // 256*256
#define NMS_THR_F 0.65f
#define MAPS_INIT 0x39E3BFFFu   // order-preserving encode of -1e4f

typedef unsigned long long ull;

// order-preserving float->u32 encode (monotone: larger float => larger uint)
__device__ __forceinline__ unsigned enc_f32(float f) {
    unsigned u = __float_as_uint(f);
    return (u & 0x80000000u) ? ~u : (u | 0x80000000u);
}
__device__ __forceinline__ float dec_f32(unsigned k) {
    unsigned u = (k & 0x80000000u) ? (k ^ 0x80000000u) : ~k;
    return __uint_as_float(u);
}

// ---- K0: init maps to encode(-1e4); zero hist; zero mode ----
__global__ void k_init(uint4* __restrict__ maps4, unsigned* __restrict__ hist,
                       unsigned* __restrict__ mode_flag) {
    int b = blockIdx.x, tid = threadIdx.x;
    if (b < 6400) {                                    // 6400*256 == 1,638,400 exact
        uint4 v; v.x = v.y = v.z = v.w = MAPS_INIT;
        maps4[b * 256 + tid] = v;
    } else {
        int j = (b - 6400) * 256 + tid;                // 257 blocks cover 65536+1
        if (j < HBN) hist[j] = 0u;
        if (j == HBN) *mode_flag = 0u;
    }
}

// ---- K1: grid-parallel sigmoid + key build + GLOBAL histogram (no LDS contention) ----
__global__ __launch_bounds__(256) void k_sigkeys(
    const float* __restrict__ cls, const unsigned* __restrict__ refined_raw,
    ull* __restrict__ keys_g, unsigned* __restrict__ hist,
    unsigned* __restrict__ mode_flag)
{
    int tid = threadIdx.x;
    int e = blockIdx.x * 256 + tid;
    if (e < NE) {
        int q = e / NC, c = e - q * NC;
        float x = cls[q * (NC + 1) + c];
        float s = 1.f / (1.f + expf(-x));              // (0,1) -> bits monotone
        unsigned bits = __float_as_uint(s);
        keys_g[e] = ((ull)bits << 32) | (unsigned)(0xFFFFFFFFu - (unsigned)e);
        atomicAdd(&hist[min(bits >> 14, (unsigned)(HBN - 1))], 1u);
    }
    if (blockIdx.x == 0) {                             // dtype probe: packed-bool words >1
        unsigned bad = 0;
        #pragma unroll
        for (int j = 0; j < 4; j++) bad |= (refined_raw[tid + 256 * j] > 1u) ? 1u : 0u;
        if (bad) atomicOr(mode_flag, 1u);
    }
}

// ---- K2: single-wave boundary scan over hist (top-down) -> bn = {B, n} ----
__global__ __launch_bounds__(64) void k_boundary(
    const unsigned* __restrict__ hist, int* __restrict__ bn)
{
    int lane = threadIdx.x;
    int acc = 0;
    for (int base = HBN - 64; base >= 0; base -= 64) { // boundary ~bucket 64870: ~11 iters
        unsigned h = hist[base + lane];
        unsigned r = h;
        #pragma unroll
        for (int d = 1; d < 64; d <<= 1) {
            unsigned t2 = __shfl_down(r, d, 64);
            if (lane + d < 64) r += t2;                // r = sum h[lane..63] of chunk
        }
        ull m = __ballot(acc + (int)r >= CAND);
        if (m) {
            int hi = 63 - __clzll(m);                  // highest bucket with cum>=CAND
            int rB = __shfl((int)r, hi, 64);
            if (lane == 0) { bn[0] = base + hi; bn[1] = acc + rB; }   // n = above+hist[B]
            return;
        }
        acc += __shfl((int)r, 0, 64);                  // add chunk total
    }
    if (lane == 0) { bn[0] = 0; bn[1] = NE; }          // unreachable (cum>=1000 always)
}

// ---- K3: compact keys >= bucket B, sort descending, decode top-1000 candidates ----
__global__ __launch_bounds__(1024) void k_sortsel(
    const ull* __restrict__ keys_g, const float* __restrict__ pboxes,
    const int* __restrict__ bn,
    float4* __restrict__ cboxes, float* __restrict__ cscore,
    int* __restrict__ cfeat, int* __restrict__ clabel)
{
    __shared__ ull sbuf[2048];                         // 16 KB
    __shared__ int sCount;
    int tid = threadIdx.x;
    if (tid == 0) sCount = 0;
    __syncthreads();
    unsigned B = (unsigned)bn[0];

    #pragma unroll
    for (int k = 0; k < 24; k++) {                     // compact qualifying keys
        int e = tid + (k << 10);
        if (e < NE) {
            ull key = keys_g[e];
            if ((unsigned)(key >> 46) >= B) {          // key>>46 == bits>>14
                int pos = atomicAdd(&sCount, 1);
                if (pos < 2048) sbuf[pos] = key;
            }
        }
    }
    __syncthreads();
    int n = min(sCount, 2048);                         // ~23/bucket: n in [1000,~1023]

    if (n <= 1024) {
        // fast path: one key per thread, descending bitonic, shfl for j<64
        ull r = (tid < n) ? sbuf[tid] : 0ULL;
        for (int k = 2; k <= 1024; k <<= 1) {
            for (int j = k >> 1; j > 0; j >>= 1) {
                ull p;
                if (j >= 64) {
                    sbuf[tid] = r; __syncthreads();
                    p = sbuf[tid ^ j]; __syncthreads();
                } else {
                    p = __shfl_xor(r, j, 64);
                }
                bool d = (tid & k) != 0, lower = (tid & j) == 0;
                r = (d != lower) ? (r > p ? r : p) : (r < p ? r : p);
            }
        }
        sbuf[tid] = r;
        __syncthreads();
    } else {
        // fallback: 2048-wide LDS bitonic
        for (int i = n + tid; i < 2048; i += 1024) sbuf[i] = 0ULL;
        __syncthreads();
        for (int k = 2; k <= 2048; k <<= 1)
            for (int j = k >> 1; j > 0; j >>= 1) {
                for (int i = tid; i < 2048; i += 1024) {
                    int ixj = i ^ j;
                    if (ixj > i) {
                        ull a = sbuf[i], b2 = sbuf[ixj];
                        bool up = ((i & k) == 0);
                        if (up ? (a < b2) : (a > b2)) { sbuf[i] = b2; sbuf[ixj] = a; }
                    }
                }
                __syncthreads();
            }
    }

    if (tid < CAND) {                                  // decode + class-offset boxes
        ull key = sbuf[tid];
        unsigned bits = (unsigned)(key >> 32);
        unsigned e = 0xFFFFFFFFu - (unsigned)(key & 0xFFFFFFFFu);
        int feat = (int)e / NC, lab = (int)e - feat * NC;
        cscore[tid] = __uint_as_float(bits);
        cfeat[tid]  = feat;
        clabel[tid] = lab;
        float off = 4.f * (float)lab;
        float4 pb = ((const float4*)pboxes)[feat];
        float4 b;
        b.x = pb.x + off; b.y = pb.y + off; b.z = pb.z + off; b.w = pb.w + off;
        cboxes[tid] = b;
    }
}

// ---- K4: per-label NMS (16 waves x 5 labels) + pick first-100 + slot tables ----
__global__ __launch_bounds__(1024) void k_nms_pick(
    const float4* __restrict__ cboxes, const float* __restrict__ cscore,
    const int* __restrict__ cfeat, const int* __restrict__ clabel,
    float* __restrict__ sel_score_g, int* __restrict__ sel_slot_g,
    int* __restrict__ qry2slot_g)
{
    __shared__ unsigned char skeep[CAND];
    __shared__ int wlist[16][64];
    __shared__ int q2s[NQ];
    __shared__ float ss[KSEL]; __shared__ int sf[KSEL];
    int tid = threadIdx.x, lane = tid & 63, wv = tid >> 6;

    for (int li = 0; li < 5; li++) {                   // labels wv, wv+16, ..., wv+64
        int lab = wv + (li << 4);
        int nb = 0;
        for (int c = 0; c < CAND; c += 64) {           // ordered per-label compaction
            int i = c + lane;
            bool m = (i < CAND) && (clabel[i] == lab);
            ull bal = __ballot(m);
            if (m) {
                int r = nb + __popcll(bal & ((1ULL << lane) - 1ULL));
                if (r < 64) wlist[wv][r] = i;
            }
            nb += __popcll(bal);
        }
        int nl = min(nb, 64);                          // Binomial(1000,1/80): P(>64)~0
        __syncthreads();                               // uniform: 5 iters in all waves

        bool alive = lane < nl;
        float bxv = 0.f, byv = 0.f, bzv = 0.f, bwv = 0.f, ar = 0.f;
        int idx = -1;
        if (alive) {
            idx = wlist[wv][lane];
            float4 cb = cboxes[idx];
            bxv = cb.x; byv = cb.y; bzv = cb.z; bwv = cb.w;
            ar = (bzv - bxv) * (bwv - byv);
        }
        bool keep = alive;
        for (int i = 0; i < nl; i++) {                 // sequential greedy, score order
            float bix = __shfl(bxv, i), biy = __shfl(byv, i);
            float biz = __shfl(bzv, i), biw = __shfl(bwv, i);
            float ai  = __shfl(ar, i);
            int   ki  = __shfl((int)keep, i);
            if (ki && keep && lane > i) {
                float xx1 = fmaxf(bix, bxv), yy1 = fmaxf(biy, byv);
                float xx2 = fminf(biz, bzv), yy2 = fminf(biw, bwv);
                float inter = fmaxf(xx2 - xx1, 0.f) * fmaxf(yy2 - yy1, 0.f);
                float uni = ai + ar - inter;
                if (inter / fmaxf(uni, 1e-9f) > NMS_THR_F) keep = false;
            }
        }
        if (alive) skeep[idx] = keep ? 1 : 0;
    }
    __syncthreads();

    // pick: first-100 kept in sorted order; parallel dedup/slot assignment (wave 0)
    for (int q = tid; q < NQ; q += 1024) q2s[q] = -1;
    __syncthreads();
    if (tid < 64) {
        int base = 0;
        for (int c = 0; c < CAND; c += 64) {
            int i = c + lane;
            bool k2 = (i < CAND) && skeep[i];
            ull bal = __ballot(k2);
            int pos = base + __popcll(bal & ((1ULL << lane) - 1ULL));
            if (k2 && pos < KSEL) { ss[pos] = cscore[i]; sf[pos] = cfeat[i]; }
            base += __popcll(bal);
        }
        int nsel = min(base, KSEL);
        int s1 = lane, s2 = lane + 64;                 // positions 0..63, 64..127
        int fp1 = s1, fp2 = s2;
        if (s1 < nsel) { int f = sf[s1]; for (int k2 = 0; k2 < s1; k2++) if (sf[k2] == f) { fp1 = k2; break; } }
        if (s2 < nsel) { int f = sf[s2]; for (int k2 = 0; k2 < s2; k2++) if (sf[k2] == f) { fp2 = k2; break; } }
        bool fo1 = (s1 < nsel) && (fp1 == s1);
        bool fo2 = (s2 < nsel) && (fp2 == s2);
        ull b1 = __ballot(fo1);
        ull b2 = __ballot(fo2);
        int c1 = __popcll(b1);
        int slot1 = -1, slot2 = -1;                    // slot = #first-occs before fp
        if (s1 < nsel) slot1 = __popcll(b1 & ((1ULL << fp1) - 1ULL));
        if (s2 < nsel) slot2 = (fp2 < 64) ? __popcll(b1 & ((1ULL << fp2) - 1ULL))
                                          : c1 + __popcll(b2 & ((1ULL << (fp2 - 64)) - 1ULL));
        sel_slot_g[s1] = slot1;
        sel_score_g[s1] = (s1 < nsel) ? ss[s1] : 0.f;  // -inf pads -> exact 0 rows
        if (s2 < KSEL) {
            sel_slot_g[s2] = slot2;
            sel_score_g[s2] = (s2 < nsel) ? ss[s2] : 0.f;
        }
        if (fo1) q2s[sf[s1]] = slot1;
        if (fo2) q2s[sf[s2]] = slot2;
    }
    __syncthreads();
    for (int q = tid; q < NQ; q += 1024) qry2slot_g[q] = q2s[q];
}

// ------- K5: scatter-max, 4 pairs/thread, all loads unconditional ----------------
__global__ __launch_bounds__(256) void k_scatter(
    const float* __restrict__ seg, const float2* __restrict__ xy,
    const int* __restrict__ qry, const unsigned* __restrict__ refined_raw,
    const int* __restrict__ qry2slot, const unsigned* __restrict__ mode_flag,
    unsigned* __restrict__ maps)
{
    int t = blockIdx.x * 256 + threadIdx.x;
    if ((t << 2) >= NPAIRS) return;

    int4 q4     = ((const int4*)qry)[t];
    float4 sg   = ((const float4*)seg)[t];
    float4 xy01 = ((const float4*)xy)[2 * t];
    float4 xy23 = ((const float4*)xy)[2 * t + 1];
    unsigned r0, r1, r2, r3;
    if (*mode_flag) {                                  // packed bool bytes
        unsigned rb = refined_raw[t];
        r0 = rb & 255u; r1 = (rb >> 8) & 255u; r2 = (rb >> 16) & 255u; r3 = rb >> 24;
    } else {                                           // int32 words
        uint4 rr = ((const uint4*)refined_raw)[t];
        r0 = rr.x; r1 = rr.y; r2 = rr.z; r3 = rr.w;
    }
    int s0 = qry2slot[q4.x], s1 = qry2slot[q4.y];
    int s2 = qry2slot[q4.z], s3 = qry2slot[q4.w];

    #define DO_PAIR(S, PX, PY, W, R)                                              \
        if (S >= 0) {                                                             \
            int px = min(max((int)((PX) * 256.f), 0), 255);                       \
            int py = min(max((int)((PY) * 256.f), 0), 255);                       \
            float w = (R) ? 2.f * (W) : (W);                                      \
            atomicMax(&maps[S * FHW + py * 256 + px], enc_f32(w));                \
        }
    DO_PAIR(s0, xy01.x, xy01.y, sg.x, r0)
    DO_PAIR(s1, xy01.z, xy01.w, sg.y, r1)
    DO_PAIR(s2, xy23.x, xy23.y, sg.z, r2)
    DO_PAIR(s3, xy23.z, xy23.w, sg.w, r3)
    #undef DO_PAIR
}

// ---------------- K6: epilogue  out = score * sigmoid(map), 4 cells/thread --------
__global__ __launch_bounds__(256) void k_output(
    const uint4* __restrict__ maps4,
    const float* __restrict__ sel_score, const int* __restrict__ sel_slot,
    float4* __restrict__ out4)
{
    int i = blockIdx.x * 256 + threadIdx.x;            // 6400*256 == 1,638,400 exact
    int s = i >> 14;                                   // 16384 uint4 per segment
    float sc = sel_score[s];
    int slot = sel_slot[s];
    float4 v = {0.f, 0.f, 0.f, 0.f};
    if (slot >= 0) {
        uint4 m = maps4[slot * (FHW / 4) + (i & 16383)];
        v.x = sc / (1.f + expf(-dec_f32(m.x)));        // m=-1e4 -> exp=inf -> exactly 0
        v.y = sc / (1.f + expf(-dec_f32(m.y)));
        v.z = sc / (1.f + expf(-dec_f32(m.z)));
        v.w = sc / (1.f + expf(-dec_f32(m.w)));
    }
    out4[i] = v;
}

// ---------------- launch ----------------
extern "C" void kernel_launch(void* const* d_in, const int* in_sizes, int n_in,
                              void* d_out, int out_size, void* d_ws, size_t ws_size,
                              hipStream_t stream) {
    const float*    cls     = (const float*)d_in[0];
    const float*    pboxes  = (const float*)d_in[1];
    const float*    seg     = (const float*)d_in[2];
    const float2*   xy      = (const float2*)d_in[3];
    const int*      qry     = (const int*)d_in[4];
    const unsigned* refined = (const unsigned*)d_in[5];
    // d_in[6] map_ids: unused by the reference
    float* out = (float*)d_out;

    // selection scratch lives in d_out (k_output overwrites every byte at the end)
    char* ob = (char*)d_out;
    ull*      keys   = (ull*)ob;                       // 0 .. 192,000 B
    unsigned* hist   = (unsigned*)(ob + 196608);       // 256 KB (65536 buckets)
    float4*   cboxes = (float4*)(ob + 458752);         // 16,000 B (16-aligned)
    float*    cscore = (float*)(ob + 474752);          // 4,000 B
    int*      cfeat  = (int*)(ob + 478752);            // 4,000 B
    int*      clabel = (int*)(ob + 482752);            // 4,000 B
    int*      bn     = (int*)(ob + 486752);            // 8 B {B, n}

    char* ws = (char*)d_ws;
    unsigned* maps      = (unsigned*)ws;               // 26,214,400 B
    float*    sel_score = (float*)   (ws + 26214400);  // 400 B
    int*      sel_slot  = (int*)     (ws + 26214800);  // 400 B
    int*      qry2slot  = (int*)     (ws + 26215200);  // 1,200 B
    unsigned* mode_flag = (unsigned*)(ws + 26216400);  // 4 B

    k_init    <<<6657, 256, 0, stream>>>((uint4*)maps, hist, mode_flag);
    k_sigkeys <<<94, 256, 0, stream>>>(cls, refined, keys, hist, mode_flag);
    k_boundary<<<1, 64, 0, stream>>>(hist, bn);
    k_sortsel <<<1, 1024, 0, stream>>>(keys, pboxes, bn, cboxes, cscore, cfeat, clabel);
    k_nms_pick<<<1, 1024, 0, stream>>>(cboxes, cscore, cfeat, clabel,
                                       sel_score, sel_slot, qry2slot);
    k_scatter <<<3907, 256, 0, stream>>>(seg, xy, qry, refined, qry2slot, mode_flag, maps);
    k_output  <<<6400, 256, 0, stream>>>((const uint4*)maps, sel_score, sel_slot,
                                         (float4*)out);
}